// Round 1
// baseline (601.873 us; speedup 1.0000x reference)
//
#include <hip/hip_runtime.h>
#include <hip/hip_bf16.h>

#define NN 50000
#define EE 800000

typedef __attribute__((ext_vector_type(8))) short short8;
typedef __attribute__((ext_vector_type(4))) short short4v;
typedef __attribute__((ext_vector_type(4))) float f32x4;

__device__ __forceinline__ float bf2f(ushort u) {
  union { unsigned u; float f; } v; v.u = ((unsigned)u) << 16; return v.f;
}
__device__ __forceinline__ ushort f2bf(float f) {
  union { float f; unsigned u; } v; v.f = f;
  unsigned r = v.u + 0x7FFFu + ((v.u >> 16) & 1u);  // RNE
  return (ushort)(r >> 16);
}

// ---- prep: h (f32 [N][128]) -> bf16 copy ----
__global__ void prep_h_kernel(const float* __restrict__ h, ushort* __restrict__ hb) {
  int i = blockIdx.x * 256 + threadIdx.x;           // 8 elems per thread
  const float4* p = (const float4*)h;
  float4 a = p[2*i], b = p[2*i+1];
  short8 o;
  o[0]=f2bf(a.x); o[1]=f2bf(a.y); o[2]=f2bf(a.z); o[3]=f2bf(a.w);
  o[4]=f2bf(b.x); o[5]=f2bf(b.y); o[6]=f2bf(b.z); o[7]=f2bf(b.w);
  *(short8*)(hb + 8*i) = o;
}

// ---- prep: weights -> transposed bf16 [n][k] ----
__global__ void prep_w_kernel(const float* __restrict__ W1, const float* __restrict__ W2,
                              const float* __restrict__ W3,
                              ushort* __restrict__ W1t, ushort* __restrict__ W2t,
                              ushort* __restrict__ W3t) {
  int i = blockIdx.x * 256 + threadIdx.x;
  if (i < 32768) {                       // W1t [128][256]
    int n = i >> 8, k = i & 255;
    W1t[i] = f2bf(W1[k*128 + n]);
  } else if (i < 49152) {                // W2t [128][128]
    int j = i - 32768, n = j >> 7, k = j & 127;
    W2t[j] = f2bf(W2[k*128 + n]);
  } else if (i < 51200) {                // W3t [16][128], rows 9..15 zero
    int j = i - 49152, n = j >> 7, k = j & 127;
    W3t[j] = (n < 9) ? f2bf(W3[k*9 + n]) : (ushort)0;
  }
}

// LN + SiLU: reads pre-LN transposed tile smT [128 n][72 stride e] (bf16),
// writes swizzled x-tile smX [64 e][128 n] (bf16). lane = edge, wave = col-quarter.
__device__ __forceinline__ void ln_silu(const ushort* smT, ushort* smX,
                                        float* smRedS, float* smRedQ,
                                        const float* __restrict__ g,
                                        const float* __restrict__ be,
                                        int lane, int w) {
  int e = lane, n0 = w * 32;
  float s = 0.f, q = 0.f;
  #pragma unroll
  for (int i = 0; i < 32; ++i) {
    float f = bf2f(smT[(n0 + i)*72 + e]);
    s += f; q += f*f;
  }
  smRedS[w*64 + e] = s; smRedQ[w*64 + e] = q;
  __syncthreads();
  s = smRedS[e] + smRedS[64+e] + smRedS[128+e] + smRedS[192+e];
  q = smRedQ[e] + smRedQ[64+e] + smRedQ[128+e] + smRedQ[192+e];
  float m  = s * (1.f/128.f);
  float rs = rsqrtf(q * (1.f/128.f) - m*m + 1e-5f);
  #pragma unroll
  for (int c = 0; c < 4; ++c) {
    short8 o;
    #pragma unroll
    for (int j = 0; j < 8; ++j) {
      int i = c*8 + j;
      float f = bf2f(smT[(n0 + i)*72 + e]);
      float v = (f - m) * rs * g[n0 + i] + be[n0 + i];
      v = v * (1.f / (1.f + __expf(-v)));        // SiLU
      o[j] = f2bf(v);
    }
    int bo = (e*256 + (n0 + c*8)*2) ^ ((e & 7) << 4);
    *(short8*)((char*)smX + bo) = o;
  }
}

template<bool USE_HB>
__global__ __launch_bounds__(256, 2)
void edge_kernel(const float* __restrict__ h, const ushort* __restrict__ hb,
                 const ushort* __restrict__ W1t, const ushort* __restrict__ W2t,
                 const ushort* __restrict__ W3t,
                 const float* __restrict__ W1,
                 const float* __restrict__ b1, const float* __restrict__ g1, const float* __restrict__ be1,
                 const float* __restrict__ b2, const float* __restrict__ g2, const float* __restrict__ be2,
                 const float* __restrict__ edge_attr, const float* __restrict__ edge_mask,
                 const float* __restrict__ coord_diff,
                 const int* __restrict__ row, const int* __restrict__ col,
                 float* __restrict__ agg) {
  __shared__ __align__(16) ushort smA[64*256];   // gathered A-tile, XOR-swizzled
  __shared__ __align__(16) ushort smT[128*72];   // pre-LN, transposed [n][e]
  __shared__ __align__(16) ushort smX[64*128];   // post-LN x, XOR-swizzled
  __shared__ float smCd[64*9];
  __shared__ float smPhi[64*12];
  __shared__ float smRedS[256];
  __shared__ float smRedQ[256];
  __shared__ float smEA[64];
  __shared__ float smEM[64];
  __shared__ int   smRow[64];

  const int tid  = threadIdx.x;
  const int lane = tid & 63;
  const int w    = tid >> 6;
  const int l15  = lane & 15;
  const int lh   = lane >> 4;
  const int wm   = w >> 1;     // M-split (rows wm*32..)
  const int wn   = w & 1;      // N-split (cols wn*64..)
  const int e0   = blockIdx.x * 64;

  // ---- gather A = [h[row] ++ h[col]] as bf16, swizzled ----
  {
    int e = tid >> 2, p = tid & 3;
    int re = row[e0 + e], ce = col[e0 + e];
    if (p == 0) { smEA[e] = edge_attr[e0+e]; smEM[e] = edge_mask[e0+e]; smRow[e] = re; }
    if (USE_HB) {
      const ushort* s = hb + (size_t)((p & 2) ? ce : re) * 128 + (p & 1) * 64;
      #pragma unroll
      for (int c = 0; c < 8; ++c) {
        short8 v = *(const short8*)(s + c*8);
        int bo = (e*512 + (p*8 + c)*16) ^ ((e & 7) << 4);
        *(short8*)((char*)smA + bo) = v;
      }
    } else {
      const float* s = h + (size_t)((p & 2) ? ce : re) * 128 + (p & 1) * 64;
      #pragma unroll
      for (int c = 0; c < 8; ++c) {
        float4 a = *(const float4*)(s + c*8);
        float4 b = *(const float4*)(s + c*8 + 4);
        short8 v;
        v[0]=f2bf(a.x); v[1]=f2bf(a.y); v[2]=f2bf(a.z); v[3]=f2bf(a.w);
        v[4]=f2bf(b.x); v[5]=f2bf(b.y); v[6]=f2bf(b.z); v[7]=f2bf(b.w);
        int bo = (e*512 + (p*8 + c)*16) ^ ((e & 7) << 4);
        *(short8*)((char*)smA + bo) = v;
      }
    }
  }
  if (tid < 144)
    *(float4*)(smCd + tid*4) = *(const float4*)(coord_diff + (size_t)e0*9 + tid*4);
  __syncthreads();

  // ---- GEMM1: [64x256] @ W1t -> pre-LN1 ----
  f32x4 acc[2][4] = {};
  {
    const ushort* Wp[4];
    #pragma unroll
    for (int nf = 0; nf < 4; ++nf)
      Wp[nf] = W1t + (size_t)(wn*64 + nf*16 + l15) * 256 + lh*8;
    #pragma unroll
    for (int k0 = 0; k0 < 8; ++k0) {
      short8 b[4];
      #pragma unroll
      for (int nf = 0; nf < 4; ++nf) b[nf] = *(const short8*)(Wp[nf] + k0*32);
      #pragma unroll
      for (int mi = 0; mi < 2; ++mi) {
        int r = wm*32 + mi*16 + l15;
        int bo = (r*512 + k0*64 + lh*16) ^ ((r & 7) << 4);
        short8 a = *(const short8*)((char*)smA + bo);
        #pragma unroll
        for (int nf = 0; nf < 4; ++nf)
          acc[mi][nf] = __builtin_amdgcn_mfma_f32_16x16x32_bf16(a, b[nf], acc[mi][nf], 0, 0, 0);
      }
    }
  }
  {
    const float* w1last = W1 + 256*128;
    #pragma unroll
    for (int nf = 0; nf < 4; ++nf) {
      int n = wn*64 + nf*16 + l15;
      float bb = b1[n], wl = w1last[n];
      #pragma unroll
      for (int mi = 0; mi < 2; ++mi) {
        int r0 = wm*32 + mi*16 + lh*4;
        short4v o;
        #pragma unroll
        for (int j = 0; j < 4; ++j)
          o[j] = f2bf(acc[mi][nf][j] + bb + smEA[r0 + j] * wl);
        *(short4v*)(smT + n*72 + r0) = o;
      }
    }
  }
  __syncthreads();
  ln_silu(smT, smX, smRedS, smRedQ, g1, be1, lane, w);
  __syncthreads();

  // ---- GEMM2: [64x128] @ W2t -> pre-LN2 ----
  f32x4 acc2[2][4] = {};
  {
    const ushort* Wp[4];
    #pragma unroll
    for (int nf = 0; nf < 4; ++nf)
      Wp[nf] = W2t + (size_t)(wn*64 + nf*16 + l15) * 128 + lh*8;
    #pragma unroll
    for (int k0 = 0; k0 < 4; ++k0) {
      short8 b[4];
      #pragma unroll
      for (int nf = 0; nf < 4; ++nf) b[nf] = *(const short8*)(Wp[nf] + k0*32);
      #pragma unroll
      for (int mi = 0; mi < 2; ++mi) {
        int r = wm*32 + mi*16 + l15;
        int bo = (r*256 + k0*64 + lh*16) ^ ((r & 7) << 4);
        short8 a = *(const short8*)((char*)smX + bo);
        #pragma unroll
        for (int nf = 0; nf < 4; ++nf)
          acc2[mi][nf] = __builtin_amdgcn_mfma_f32_16x16x32_bf16(a, b[nf], acc2[mi][nf], 0, 0, 0);
      }
    }
  }
  {
    #pragma unroll
    for (int nf = 0; nf < 4; ++nf) {
      int n = wn*64 + nf*16 + l15;
      float bb = b2[n];
      #pragma unroll
      for (int mi = 0; mi < 2; ++mi) {
        int r0 = wm*32 + mi*16 + lh*4;
        short4v o;
        #pragma unroll
        for (int j = 0; j < 4; ++j) o[j] = f2bf(acc2[mi][nf][j] + bb);
        *(short4v*)(smT + n*72 + r0) = o;
      }
    }
  }
  __syncthreads();
  ln_silu(smT, smX, smRedS, smRedQ, g2, be2, lane, w);
  __syncthreads();

  // ---- GEMM3: phi = x3 @ W3 ([64x128]@[128x9], N padded to 16) ----
  {
    f32x4 acc3 = {};
    const ushort* Wp = W3t + (size_t)l15*128 + lh*8;
    #pragma unroll
    for (int k0 = 0; k0 < 4; ++k0) {
      short8 b = *(const short8*)(Wp + k0*32);
      int r = w*16 + l15;
      int bo = (r*256 + k0*64 + lh*16) ^ ((r & 7) << 4);
      short8 a = *(const short8*)((char*)smX + bo);
      acc3 = __builtin_amdgcn_mfma_f32_16x16x32_bf16(a, b, acc3, 0, 0, 0);
    }
    if (l15 < 9) {
      #pragma unroll
      for (int j = 0; j < 4; ++j)
        smPhi[(w*16 + lh*4 + j)*12 + l15] = acc3[j];
    }
  }
  __syncthreads();

  // ---- trans[l][k] = sum_j cd[j][k]*phi[j][l]; scatter-add to agg[row] ----
  {
    int e = tid >> 2, q = tid & 3;
    int re = smRow[e];
    float em = smEM[e];
    const float* cd = smCd + e*9;
    const float* ph = smPhi + e*12;
    for (int idx = q; idx < 9; idx += 4) {
      int l2 = idx / 3, k = idx - l2*3;
      float t = cd[k]*ph[l2] + cd[3+k]*ph[3+l2] + cd[6+k]*ph[6+l2];
      unsafeAtomicAdd(&agg[(size_t)re*9 + idx], t * em);
    }
  }
}

__global__ void finalize_kernel(const float* __restrict__ coord, const float* __restrict__ node_mask,
                                const float* __restrict__ agg, float* __restrict__ out) {
  int i = blockIdx.x * 256 + threadIdx.x;
  if (i < NN*9) {
    int n = i / 9;
    out[i] = (coord[i] + agg[i] * 0.01f) * node_mask[n];
  }
}

extern "C" void kernel_launch(void* const* d_in, const int* in_sizes, int n_in,
                              void* d_out, int out_size, void* d_ws, size_t ws_size,
                              hipStream_t stream) {
  const float* h          = (const float*)d_in[0];
  const float* coord      = (const float*)d_in[1];
  const float* coord_diff = (const float*)d_in[2];
  const float* edge_attr  = (const float*)d_in[3];
  const float* edge_mask  = (const float*)d_in[4];
  const float* node_mask  = (const float*)d_in[5];
  const int*   rowi       = (const int*)d_in[6];
  const int*   coli       = (const int*)d_in[7];
  const float* W1  = (const float*)d_in[8];
  const float* b1  = (const float*)d_in[9];
  const float* g1  = (const float*)d_in[10];
  const float* be1 = (const float*)d_in[11];
  const float* W2  = (const float*)d_in[12];
  const float* b2  = (const float*)d_in[13];
  const float* g2  = (const float*)d_in[14];
  const float* be2 = (const float*)d_in[15];
  const float* W3  = (const float*)d_in[16];

  char* ws = (char*)d_ws;
  float*  agg = (float*)ws;                        // 1,800,000 B
  ushort* W1t = (ushort*)(ws + 1800064);           // 65,536 B
  ushort* W2t = (ushort*)(ws + 1865600);           // 32,768 B
  ushort* W3t = (ushort*)(ws + 1898368);           // 4,096 B
  ushort* hb  = (ushort*)(ws + 1902464);           // 12,800,000 B
  bool use_hb = ws_size >= (size_t)1902464 + 12800000;

  hipMemsetAsync(agg, 0, (size_t)NN*9*sizeof(float), stream);
  prep_w_kernel<<<200, 256, 0, stream>>>(W1, W2, W3, W1t, W2t, W3t);
  if (use_hb) {
    prep_h_kernel<<<NN*128/(8*256), 256, 0, stream>>>(h, hb);
    edge_kernel<true><<<EE/64, 256, 0, stream>>>(h, hb, W1t, W2t, W3t, W1,
        b1, g1, be1, b2, g2, be2, edge_attr, edge_mask, coord_diff, rowi, coli, agg);
  } else {
    edge_kernel<false><<<EE/64, 256, 0, stream>>>(h, hb, W1t, W2t, W3t, W1,
        b1, g1, be1, b2, g2, be2, edge_attr, edge_mask, coord_diff, rowi, coli, agg);
  }
  finalize_kernel<<<(NN*9 + 255)/256, 256, 0, stream>>>(coord, node_mask, agg, (float*)d_out);
}

// Round 2
// 519.698 us; speedup vs baseline: 1.1581x; 1.1581x over previous
//
#include <hip/hip_runtime.h>
#include <hip/hip_bf16.h>

#define NN 50000
#define EE 800000

typedef __attribute__((ext_vector_type(8))) short short8;
typedef __attribute__((ext_vector_type(4))) float f32x4;

__device__ __forceinline__ float bf2f(ushort u) {
  union { unsigned u; float f; } v; v.u = ((unsigned)u) << 16; return v.f;
}
__device__ __forceinline__ ushort f2bf(float f) {
  union { float f; unsigned u; } v; v.f = f;
  unsigned r = v.u + 0x7FFFu + ((v.u >> 16) & 1u);  // RNE
  return (ushort)(r >> 16);
}

// ---- merged prep: h->bf16, weights->transposed bf16, agg zeroing ----
__global__ void prep_kernel(const float* __restrict__ h, ushort* __restrict__ hb,
                            const float* __restrict__ W1, const float* __restrict__ W2,
                            const float* __restrict__ W3,
                            ushort* __restrict__ W1t, ushort* __restrict__ W2t,
                            ushort* __restrict__ W3t, float* __restrict__ agg) {
  int b = blockIdx.x, tid = threadIdx.x;
  if (b < 3125) {                         // h -> hb, 8 elems/thread
    int i = b * 256 + tid;
    const float4* p = (const float4*)h;
    float4 a = p[2*i], c = p[2*i+1];
    short8 o;
    o[0]=f2bf(a.x); o[1]=f2bf(a.y); o[2]=f2bf(a.z); o[3]=f2bf(a.w);
    o[4]=f2bf(c.x); o[5]=f2bf(c.y); o[6]=f2bf(c.z); o[7]=f2bf(c.w);
    *(short8*)(hb + 8*i) = o;
  } else if (b < 3325) {                  // weights
    int i = (b - 3125) * 256 + tid;
    if (i < 32768) {                      // W1t [128][256]
      int n = i >> 8, k = i & 255;
      W1t[i] = f2bf(W1[k*128 + n]);
    } else if (i < 49152) {               // W2t [128][128]
      int j = i - 32768, n = j >> 7, k = j & 127;
      W2t[j] = f2bf(W2[k*128 + n]);
    } else if (i < 51200) {               // W3t [16][128], rows 9..15 zero
      int j = i - 49152, n = j >> 7, k = j & 127;
      W3t[j] = (n < 9) ? f2bf(W3[k*9 + n]) : (ushort)0;
    }
  } else {                                // zero agg
    int i = (b - 3325) * 256 + tid;
    if (i < NN*9) agg[i] = 0.f;
  }
}

// In-place LN+SiLU on smX [64 e][128 n] bf16, XOR-swizzled rows.
// lane owns (edge e = tid&63, col-quarter n0 = (tid>>6)*32).
__device__ __forceinline__ void ln_silu_inplace(ushort* smX, float* smRedS, float* smRedQ,
                                                const float* __restrict__ g,
                                                const float* __restrict__ be, int tid) {
  int e = tid & 63, w4 = tid >> 6, n0 = w4 * 32;
  float v[32]; float s = 0.f, q = 0.f;
  int bo[4];
  #pragma unroll
  for (int c = 0; c < 4; ++c) {
    bo[c] = (e*256 + (n0 + c*8)*2) ^ ((e & 7) << 4);
    short8 x = *(const short8*)((char*)smX + bo[c]);
    #pragma unroll
    for (int j = 0; j < 8; ++j) {
      float f = bf2f((ushort)x[j]); v[c*8+j] = f; s += f; q += f*f;
    }
  }
  smRedS[w4*64 + e] = s; smRedQ[w4*64 + e] = q;
  __syncthreads();
  s = smRedS[e] + smRedS[64+e] + smRedS[128+e] + smRedS[192+e];
  q = smRedQ[e] + smRedQ[64+e] + smRedQ[128+e] + smRedQ[192+e];
  float m  = s * (1.f/128.f);
  float rs = rsqrtf(q * (1.f/128.f) - m*m + 1e-5f);
  #pragma unroll
  for (int c = 0; c < 4; ++c) {
    short8 o;
    #pragma unroll
    for (int j = 0; j < 8; ++j) {
      float val = (v[c*8+j] - m) * rs * g[n0 + c*8 + j] + be[n0 + c*8 + j];
      val = val * __builtin_amdgcn_rcpf(1.f + __expf(-val));   // SiLU
      o[j] = f2bf(val);
    }
    *(short8*)((char*)smX + bo[c]) = o;
  }
  __syncthreads();
}

template<bool USE_HB>
__global__ __launch_bounds__(256, 4)
void edge_kernel(const float* __restrict__ h, const ushort* __restrict__ hb,
                 const ushort* __restrict__ W1t, const ushort* __restrict__ W2t,
                 const ushort* __restrict__ W3t,
                 const float* __restrict__ W1,
                 const float* __restrict__ b1, const float* __restrict__ g1, const float* __restrict__ be1,
                 const float* __restrict__ b2, const float* __restrict__ g2, const float* __restrict__ be2,
                 const float* __restrict__ edge_attr, const float* __restrict__ edge_mask,
                 const float* __restrict__ coord_diff,
                 const int* __restrict__ row, const int* __restrict__ col,
                 float* __restrict__ agg) {
  // LDS map (35840 B total -> 4 blocks/CU):
  //  [0..32768)   smA [64][256] bf16 swizzled (gather + GEMM1)   -- dead after GEMM1
  //  [0..16384)   smX [64][128] bf16 swizzled (x tiles)          -- aliases smA
  //  [16384..17408) smRedS, [17408..18432) smRedQ               -- alias smA upper half
  //  [18432..21504) smPhi [64][12] f32                          -- alias smA upper half
  //  [32768..35072) smCd [64][9] f32   (live from gather on -> separate)
  //  [35072..35840) smEA/smEM/smRow
  __shared__ __align__(16) char smem[35840];
  ushort* smA   = (ushort*)smem;
  ushort* smX   = (ushort*)smem;
  float*  smRedS = (float*)(smem + 16384);
  float*  smRedQ = (float*)(smem + 17408);
  float*  smPhi  = (float*)(smem + 18432);
  float*  smCd   = (float*)(smem + 32768);
  float*  smEA   = (float*)(smem + 35072);
  float*  smEM   = (float*)(smem + 35328);
  int*    smRow  = (int*)  (smem + 35584);

  const int tid  = threadIdx.x;
  const int lane = tid & 63;
  const int w    = tid >> 6;
  const int l15  = lane & 15;
  const int lh   = lane >> 4;
  const int wm   = w >> 1;     // M-split (rows wm*32..)
  const int wn   = w & 1;      // N-split (cols wn*64..)
  const int e0   = blockIdx.x * 64;

  // ---- gather A = [h[row] ++ h[col]] as bf16, swizzled ----
  {
    int e = tid >> 2, p = tid & 3;
    int re = row[e0 + e], ce = col[e0 + e];
    if (p == 0) { smEA[e] = edge_attr[e0+e]; smEM[e] = edge_mask[e0+e]; smRow[e] = re; }
    if (USE_HB) {
      const ushort* s = hb + (size_t)((p & 2) ? ce : re) * 128 + (p & 1) * 64;
      #pragma unroll
      for (int c = 0; c < 8; ++c) {
        short8 v = *(const short8*)(s + c*8);
        int bo = (e*512 + (p*8 + c)*16) ^ ((e & 7) << 4);
        *(short8*)((char*)smA + bo) = v;
      }
    } else {
      const float* s = h + (size_t)((p & 2) ? ce : re) * 128 + (p & 1) * 64;
      #pragma unroll
      for (int c = 0; c < 8; ++c) {
        float4 a = *(const float4*)(s + c*8);
        float4 bq = *(const float4*)(s + c*8 + 4);
        short8 v;
        v[0]=f2bf(a.x); v[1]=f2bf(a.y); v[2]=f2bf(a.z); v[3]=f2bf(a.w);
        v[4]=f2bf(bq.x); v[5]=f2bf(bq.y); v[6]=f2bf(bq.z); v[7]=f2bf(bq.w);
        int bo = (e*512 + (p*8 + c)*16) ^ ((e & 7) << 4);
        *(short8*)((char*)smA + bo) = v;
      }
    }
  }
  if (tid < 144)
    *(float4*)(smCd + tid*4) = *(const float4*)(coord_diff + (size_t)e0*9 + tid*4);
  __syncthreads();

  // ---- GEMM1: [64x256] @ W1t^T -> acc ----
  f32x4 acc[2][4] = {};
  {
    const ushort* Wp[4];
    #pragma unroll
    for (int nf = 0; nf < 4; ++nf)
      Wp[nf] = W1t + (size_t)(wn*64 + nf*16 + l15) * 256 + lh*8;
    #pragma unroll
    for (int k0 = 0; k0 < 8; ++k0) {
      short8 b[4];
      #pragma unroll
      for (int nf = 0; nf < 4; ++nf) b[nf] = *(const short8*)(Wp[nf] + k0*32);
      #pragma unroll
      for (int mi = 0; mi < 2; ++mi) {
        int r = wm*32 + mi*16 + l15;
        int bo = (r*512 + k0*64 + lh*16) ^ ((r & 7) << 4);
        short8 a = *(const short8*)((char*)smA + bo);
        #pragma unroll
        for (int nf = 0; nf < 4; ++nf)
          acc[mi][nf] = __builtin_amdgcn_mfma_f32_16x16x32_bf16(a, b[nf], acc[mi][nf], 0, 0, 0);
      }
    }
  }
  __syncthreads();   // all smA reads done; smX/smRed/smPhi may now overwrite it

  // ---- epi1: raw pre-LN x1 (bf16) -> smX (in C-fragment order, swizzled) ----
  {
    const float* w1last = W1 + 256*128;
    float bbv[4], wlv[4];
    #pragma unroll
    for (int nf = 0; nf < 4; ++nf) {
      int n = wn*64 + nf*16 + l15;
      bbv[nf] = b1[n]; wlv[nf] = w1last[n];
    }
    #pragma unroll
    for (int mi = 0; mi < 2; ++mi) {
      int r0 = wm*32 + mi*16 + lh*4;
      float ea[4];
      #pragma unroll
      for (int j = 0; j < 4; ++j) ea[j] = smEA[r0 + j];
      #pragma unroll
      for (int nf = 0; nf < 4; ++nf) {
        int n = wn*64 + nf*16 + l15;
        #pragma unroll
        for (int j = 0; j < 4; ++j) {
          int r = r0 + j;
          float val = acc[mi][nf][j] + bbv[nf] + ea[j] * wlv[nf];
          *(ushort*)((char*)smX + ((r*256 + n*2) ^ ((r & 7) << 4))) = f2bf(val);
        }
      }
    }
  }
  __syncthreads();
  ln_silu_inplace(smX, smRedS, smRedQ, g1, be1, tid);

  // ---- GEMM2: [64x128] @ W2t^T ----
  f32x4 acc2[2][4] = {};
  {
    const ushort* Wp[4];
    #pragma unroll
    for (int nf = 0; nf < 4; ++nf)
      Wp[nf] = W2t + (size_t)(wn*64 + nf*16 + l15) * 128 + lh*8;
    #pragma unroll
    for (int k0 = 0; k0 < 4; ++k0) {
      short8 b[4];
      #pragma unroll
      for (int nf = 0; nf < 4; ++nf) b[nf] = *(const short8*)(Wp[nf] + k0*32);
      #pragma unroll
      for (int mi = 0; mi < 2; ++mi) {
        int r = wm*32 + mi*16 + l15;
        int bo = (r*256 + k0*64 + lh*16) ^ ((r & 7) << 4);
        short8 a = *(const short8*)((char*)smX + bo);
        #pragma unroll
        for (int nf = 0; nf < 4; ++nf)
          acc2[mi][nf] = __builtin_amdgcn_mfma_f32_16x16x32_bf16(a, b[nf], acc2[mi][nf], 0, 0, 0);
      }
    }
  }
  __syncthreads();   // all smX (x1) reads done before in-place overwrite

  // ---- epi2: raw pre-LN x2 -> smX in place ----
  {
    float bbv[4];
    #pragma unroll
    for (int nf = 0; nf < 4; ++nf) bbv[nf] = b2[wn*64 + nf*16 + l15];
    #pragma unroll
    for (int mi = 0; mi < 2; ++mi) {
      int r0 = wm*32 + mi*16 + lh*4;
      #pragma unroll
      for (int nf = 0; nf < 4; ++nf) {
        int n = wn*64 + nf*16 + l15;
        #pragma unroll
        for (int j = 0; j < 4; ++j) {
          int r = r0 + j;
          float val = acc2[mi][nf][j] + bbv[nf];
          *(ushort*)((char*)smX + ((r*256 + n*2) ^ ((r & 7) << 4))) = f2bf(val);
        }
      }
    }
  }
  __syncthreads();
  ln_silu_inplace(smX, smRedS, smRedQ, g2, be2, tid);

  // ---- GEMM3: phi = x3 @ W3 ([64x128]@[128x9], N padded to 16) ----
  {
    f32x4 acc3 = {};
    const ushort* Wp = W3t + (size_t)l15*128 + lh*8;
    #pragma unroll
    for (int k0 = 0; k0 < 4; ++k0) {
      short8 b = *(const short8*)(Wp + k0*32);
      int r = w*16 + l15;
      int bo = (r*256 + k0*64 + lh*16) ^ ((r & 7) << 4);
      short8 a = *(const short8*)((char*)smX + bo);
      acc3 = __builtin_amdgcn_mfma_f32_16x16x32_bf16(a, b, acc3, 0, 0, 0);
    }
    if (l15 < 9) {
      #pragma unroll
      for (int j = 0; j < 4; ++j)
        smPhi[(w*16 + lh*4 + j)*12 + l15] = acc3[j];
    }
  }
  __syncthreads();

  // ---- trans[l][k] = sum_j cd[j][k]*phi[j][l]; scatter-add to agg[row] ----
  {
    int e = tid >> 2, qd = tid & 3;
    int re = smRow[e];
    float em = smEM[e];
    const float* cd = smCd + e*9;
    const float* ph = smPhi + e*12;
    for (int idx = qd; idx < 9; idx += 4) {
      int l2 = idx / 3, k = idx - l2*3;
      float t = cd[k]*ph[l2] + cd[3+k]*ph[3+l2] + cd[6+k]*ph[6+l2];
      unsafeAtomicAdd(&agg[(size_t)re*9 + idx], t * em);
    }
  }
}

__global__ void finalize_kernel(const float* __restrict__ coord, const float* __restrict__ node_mask,
                                const float* __restrict__ agg, float* __restrict__ out) {
  int i = blockIdx.x * 256 + threadIdx.x;
  if (i < NN*9) {
    int n = i / 9;
    out[i] = (coord[i] + agg[i] * 0.01f) * node_mask[n];
  }
}

extern "C" void kernel_launch(void* const* d_in, const int* in_sizes, int n_in,
                              void* d_out, int out_size, void* d_ws, size_t ws_size,
                              hipStream_t stream) {
  const float* h          = (const float*)d_in[0];
  const float* coord      = (const float*)d_in[1];
  const float* coord_diff = (const float*)d_in[2];
  const float* edge_attr  = (const float*)d_in[3];
  const float* edge_mask  = (const float*)d_in[4];
  const float* node_mask  = (const float*)d_in[5];
  const int*   rowi       = (const int*)d_in[6];
  const int*   coli       = (const int*)d_in[7];
  const float* W1  = (const float*)d_in[8];
  const float* b1  = (const float*)d_in[9];
  const float* g1  = (const float*)d_in[10];
  const float* be1 = (const float*)d_in[11];
  const float* W2  = (const float*)d_in[12];
  const float* b2  = (const float*)d_in[13];
  const float* g2  = (const float*)d_in[14];
  const float* be2 = (const float*)d_in[15];
  const float* W3  = (const float*)d_in[16];

  char* ws = (char*)d_ws;
  float*  agg = (float*)ws;                        // 1,800,000 B
  ushort* W1t = (ushort*)(ws + 1800064);           // 65,536 B
  ushort* W2t = (ushort*)(ws + 1865600);           // 32,768 B
  ushort* W3t = (ushort*)(ws + 1898368);           // 4,096 B
  ushort* hb  = (ushort*)(ws + 1902464);           // 12,800,000 B
  bool use_hb = ws_size >= (size_t)1902464 + 12800000;

  if (use_hb) {
    prep_kernel<<<3325 + (NN*9 + 255)/256, 256, 0, stream>>>(h, hb, W1, W2, W3, W1t, W2t, W3t, agg);
    edge_kernel<true><<<EE/64, 256, 0, stream>>>(h, hb, W1t, W2t, W3t, W1,
        b1, g1, be1, b2, g2, be2, edge_attr, edge_mask, coord_diff, rowi, coli, agg);
  } else {
    prep_kernel<<<3325 + (NN*9 + 255)/256, 256, 0, stream>>>(h, hb, W1, W2, W3, W1t, W2t, W3t, agg);
    edge_kernel<false><<<EE/64, 256, 0, stream>>>(h, hb, W1t, W2t, W3t, W1,
        b1, g1, be1, b2, g2, be2, edge_attr, edge_mask, coord_diff, rowi, coli, agg);
  }
  finalize_kernel<<<(NN*9 + 255)/256, 256, 0, stream>>>(coord, node_mask, agg, (float*)d_out);
}

// Round 3
// 508.770 us; speedup vs baseline: 1.1830x; 1.0215x over previous
//
#include <hip/hip_runtime.h>
#include <hip/hip_bf16.h>

#define NN 50000
#define EE 800000

typedef __attribute__((ext_vector_type(8))) short short8;
typedef __attribute__((ext_vector_type(4))) short short4v;
typedef __attribute__((ext_vector_type(4))) float f32x4;

__device__ __forceinline__ float bf2f(ushort u) {
  union { unsigned u; float f; } v; v.u = ((unsigned)u) << 16; return v.f;
}
__device__ __forceinline__ ushort f2bf(float f) {
  union { float f; unsigned u; } v; v.f = f;
  unsigned r = v.u + 0x7FFFu + ((v.u >> 16) & 1u);  // RNE
  return (ushort)(r >> 16);
}
__device__ __forceinline__ float silu(float v) {
  return v * __builtin_amdgcn_rcpf(1.f + __expf(-v));
}

// ---- merged prep: h->bf16, weights->transposed bf16, agg zeroing ----
__global__ void prep_kernel(const float* __restrict__ h, ushort* __restrict__ hb,
                            const float* __restrict__ W1, const float* __restrict__ W2,
                            const float* __restrict__ W3,
                            ushort* __restrict__ W1t, ushort* __restrict__ W2t,
                            ushort* __restrict__ W3t, float* __restrict__ agg) {
  int b = blockIdx.x, tid = threadIdx.x;
  if (b < 3125) {                         // h -> hb, 8 elems/thread
    int i = b * 256 + tid;
    const float4* p = (const float4*)h;
    float4 a = p[2*i], c = p[2*i+1];
    short8 o;
    o[0]=f2bf(a.x); o[1]=f2bf(a.y); o[2]=f2bf(a.z); o[3]=f2bf(a.w);
    o[4]=f2bf(c.x); o[5]=f2bf(c.y); o[6]=f2bf(c.z); o[7]=f2bf(c.w);
    *(short8*)(hb + 8*i) = o;
  } else if (b < 3325) {                  // weights
    int i = (b - 3125) * 256 + tid;
    if (i < 32768) {                      // W1t [128 n][256 k]
      int n = i >> 8, k = i & 255;
      W1t[i] = f2bf(W1[k*128 + n]);
    } else if (i < 49152) {               // W2t [128 n][128 k]
      int j = i - 32768, n = j >> 7, k = j & 127;
      W2t[j] = f2bf(W2[k*128 + n]);
    } else if (i < 51200) {               // W3t [16 m][128 k], rows 9..15 zero
      int j = i - 49152, n = j >> 7, k = j & 127;
      W3t[j] = (n < 9) ? f2bf(W3[k*9 + n]) : (ushort)0;
    }
  } else {                                // zero agg
    int i = (b - 3325) * 256 + tid;
    if (i < NN*9) agg[i] = 0.f;
  }
}

template<bool USE_HB>
__global__ __launch_bounds__(256, 4)
void edge_kernel(const float* __restrict__ h, const ushort* __restrict__ hb,
                 const ushort* __restrict__ W1t, const ushort* __restrict__ W2t,
                 const ushort* __restrict__ W3t,
                 const float* __restrict__ W1,
                 const float* __restrict__ b1, const float* __restrict__ g1, const float* __restrict__ be1,
                 const float* __restrict__ b2, const float* __restrict__ g2, const float* __restrict__ be2,
                 const float* __restrict__ edge_attr, const float* __restrict__ edge_mask,
                 const float* __restrict__ coord_diff,
                 const int* __restrict__ row, const int* __restrict__ col,
                 float* __restrict__ agg) {
  // LDS map (36864 B -> 4 blocks/CU):
  //  [0..32768)     smA [64 e][256 k] bf16 swizzled (gather; GEMM1 B-operand). Dead after B2.
  //  [0..16384)     smX [64 e][128 n] bf16 swizzled (x1/x2) -- aliases smA, live after B2.
  //  [16384..21504) smPhi [64 e][20] f32 (written after GEMM3)  -- aliases smA.
  //  [32768..35072) smCd [64][9] f32
  //  [35072..35840) smEA / smEM / smRow
  //  [35840..36864) smRed [2 wm][2 wn][2 nf][16 l15] float2 partial (s,q)
  __shared__ __align__(16) char smem[36864];
  ushort* smA   = (ushort*)smem;
  ushort* smX   = (ushort*)smem;
  float*  smPhi = (float*)(smem + 16384);
  float*  smCd  = (float*)(smem + 32768);
  float*  smEA  = (float*)(smem + 35072);
  float*  smEM  = (float*)(smem + 35328);
  int*    smRow = (int*)  (smem + 35584);
  float2* smRed = (float2*)(smem + 35840);

  const int tid  = threadIdx.x;
  const int lane = tid & 63;
  const int w    = tid >> 6;
  const int l15  = lane & 15;
  const int lh   = lane >> 4;
  const int wm   = w >> 1;     // n-half:  rows wm*64 .. +63 of the transposed output
  const int wn   = w & 1;      // e-half:  edges wn*32 .. +31
  const int e0   = blockIdx.x * 64;

  // lane's edge per N-frag nf: e = wn*32 + nf*16 + l15
  // lane's n per M-frag mf, reg j: n = wm*64 + mf*16 + lh*4 + j
  const int nb = wm*64 + lh*4;             // base n of lane's quads (+ mf*16)

  // ---- gather A = [h[row] ++ h[col]] as bf16, swizzled ----
  {
    int e = tid >> 2, p = tid & 3;
    int re = row[e0 + e], ce = col[e0 + e];
    if (p == 0) { smEA[e] = edge_attr[e0+e]; smEM[e] = edge_mask[e0+e]; smRow[e] = re; }
    if (USE_HB) {
      const ushort* s = hb + (size_t)((p & 2) ? ce : re) * 128 + (p & 1) * 64;
      #pragma unroll
      for (int c = 0; c < 8; ++c) {
        short8 v = *(const short8*)(s + c*8);
        int bo = (e*512 + (p*8 + c)*16) ^ ((e & 7) << 4);
        *(short8*)((char*)smA + bo) = v;
      }
    } else {
      const float* s = h + (size_t)((p & 2) ? ce : re) * 128 + (p & 1) * 64;
      #pragma unroll
      for (int c = 0; c < 8; ++c) {
        float4 a = *(const float4*)(s + c*8);
        float4 bq = *(const float4*)(s + c*8 + 4);
        short8 v;
        v[0]=f2bf(a.x); v[1]=f2bf(a.y); v[2]=f2bf(a.z); v[3]=f2bf(a.w);
        v[4]=f2bf(bq.x); v[5]=f2bf(bq.y); v[6]=f2bf(bq.z); v[7]=f2bf(bq.w);
        int bo = (e*512 + (p*8 + c)*16) ^ ((e & 7) << 4);
        *(short8*)((char*)smA + bo) = v;
      }
    }
  }
  if (tid < 144)
    *(float4*)(smCd + tid*4) = *(const float4*)(coord_diff + (size_t)e0*9 + tid*4);
  __syncthreads();                                   // B1

  // ---- GEMM1-T: out1T[n][e] = sum_k W1t[n][k] * A[e][k]   (K=256) ----
  f32x4 acc[4][2] = {};                              // [mf][nf]
  {
    const ushort* A0 = W1t + (size_t)(wm*64 + l15) * 256 + lh*8;
    #pragma unroll
    for (int k0 = 0; k0 < 8; ++k0) {
      short8 a[4], b[2];
      #pragma unroll
      for (int mf = 0; mf < 4; ++mf) a[mf] = *(const short8*)(A0 + mf*4096 + k0*32);
      #pragma unroll
      for (int nf = 0; nf < 2; ++nf) {
        int e = wn*32 + nf*16 + l15;
        int bo = (e*512 + k0*64 + lh*16) ^ ((e & 7) << 4);
        b[nf] = *(const short8*)((char*)smA + bo);
      }
      #pragma unroll
      for (int mf = 0; mf < 4; ++mf)
        #pragma unroll
        for (int nf = 0; nf < 2; ++nf)
          acc[mf][nf] = __builtin_amdgcn_mfma_f32_16x16x32_bf16(a[mf], b[nf], acc[mf][nf], 0, 0, 0);
    }
  }

  // ---- epi1 (bias + edge_attr column) + LN1 stats, all in registers ----
  float s[2] = {0.f, 0.f}, q[2] = {0.f, 0.f};
  {
    const float* wl = W1 + 256*128;
    float ea[2];
    #pragma unroll
    for (int nf = 0; nf < 2; ++nf) ea[nf] = smEA[wn*32 + nf*16 + l15];
    #pragma unroll
    for (int mf = 0; mf < 4; ++mf) {
      float4 b1q = *(const float4*)(b1 + nb + mf*16);
      float4 wlq = *(const float4*)(wl + nb + mf*16);
      #pragma unroll
      for (int nf = 0; nf < 2; ++nf)
        #pragma unroll
        for (int j = 0; j < 4; ++j) {
          float t = acc[mf][nf][j] + ((const float*)&b1q)[j] + ea[nf] * ((const float*)&wlq)[j];
          acc[mf][nf][j] = t; s[nf] += t; q[nf] += t*t;
        }
    }
  }
  #pragma unroll
  for (int nf = 0; nf < 2; ++nf) {
    s[nf] += __shfl_xor(s[nf], 16, 64); s[nf] += __shfl_xor(s[nf], 32, 64);
    q[nf] += __shfl_xor(q[nf], 16, 64); q[nf] += __shfl_xor(q[nf], 32, 64);
  }
  if (lh == 0) {
    #pragma unroll
    for (int nf = 0; nf < 2; ++nf)
      smRed[((wm*2 + wn)*2 + nf)*16 + l15] = make_float2(s[nf], q[nf]);
  }
  __syncthreads();                                   // B2 (partials visible; smA dead)

  // ---- combine halves, normalize, SiLU, write x1 -> smX (bf16, swizzled) ----
  {
    float m[2], rs[2];
    #pragma unroll
    for (int nf = 0; nf < 2; ++nf) {
      float2 po = smRed[(((wm^1)*2 + wn)*2 + nf)*16 + l15];
      float S = s[nf] + po.x, Q = q[nf] + po.y;
      m[nf] = S * (1.f/128.f);
      rs[nf] = rsqrtf(Q * (1.f/128.f) - m[nf]*m[nf] + 1e-5f);
    }
    #pragma unroll
    for (int mf = 0; mf < 4; ++mf) {
      float4 gq  = *(const float4*)(g1 + nb + mf*16);
      float4 beq = *(const float4*)(be1 + nb + mf*16);
      #pragma unroll
      for (int nf = 0; nf < 2; ++nf) {
        int e = wn*32 + nf*16 + l15;
        short4v o;
        #pragma unroll
        for (int j = 0; j < 4; ++j) {
          float val = (acc[mf][nf][j] - m[nf]) * rs[nf] * ((const float*)&gq)[j] + ((const float*)&beq)[j];
          o[j] = f2bf(silu(val));
        }
        int bo = (e*256 + (nb + mf*16)*2) ^ ((e & 7) << 4);
        *(short4v*)((char*)smX + bo) = o;
      }
    }
  }
  __syncthreads();                                   // B3 (x1 visible)

  // ---- GEMM2-T: out2T[n][e] = sum_k W2t[n][k] * x1[e][k]   (K=128) ----
  f32x4 acc2[4][2] = {};
  {
    const ushort* A2 = W2t + (size_t)(wm*64 + l15) * 128 + lh*8;
    #pragma unroll
    for (int k0 = 0; k0 < 4; ++k0) {
      short8 a[4], b[2];
      #pragma unroll
      for (int mf = 0; mf < 4; ++mf) a[mf] = *(const short8*)(A2 + mf*2048 + k0*32);
      #pragma unroll
      for (int nf = 0; nf < 2; ++nf) {
        int e = wn*32 + nf*16 + l15;
        int bo = (e*256 + k0*64 + lh*16) ^ ((e & 7) << 4);
        b[nf] = *(const short8*)((char*)smX + bo);
      }
      #pragma unroll
      for (int mf = 0; mf < 4; ++mf)
        #pragma unroll
        for (int nf = 0; nf < 2; ++nf)
          acc2[mf][nf] = __builtin_amdgcn_mfma_f32_16x16x32_bf16(a[mf], b[nf], acc2[mf][nf], 0, 0, 0);
    }
  }

  // ---- epi2 (bias) + LN2 stats ----
  float s2[2] = {0.f, 0.f}, q2[2] = {0.f, 0.f};
  #pragma unroll
  for (int mf = 0; mf < 4; ++mf) {
    float4 b2q = *(const float4*)(b2 + nb + mf*16);
    #pragma unroll
    for (int nf = 0; nf < 2; ++nf)
      #pragma unroll
      for (int j = 0; j < 4; ++j) {
        float t = acc2[mf][nf][j] + ((const float*)&b2q)[j];
        acc2[mf][nf][j] = t; s2[nf] += t; q2[nf] += t*t;
      }
  }
  #pragma unroll
  for (int nf = 0; nf < 2; ++nf) {
    s2[nf] += __shfl_xor(s2[nf], 16, 64); s2[nf] += __shfl_xor(s2[nf], 32, 64);
    q2[nf] += __shfl_xor(q2[nf], 16, 64); q2[nf] += __shfl_xor(q2[nf], 32, 64);
  }
  if (lh == 0) {
    #pragma unroll
    for (int nf = 0; nf < 2; ++nf)
      smRed[((wm*2 + wn)*2 + nf)*16 + l15] = make_float2(s2[nf], q2[nf]);
  }
  __syncthreads();                                   // B4 (partials visible; x1 reads done)

  // ---- LN2 + SiLU, write x2 -> smX in place ----
  {
    float m[2], rs[2];
    #pragma unroll
    for (int nf = 0; nf < 2; ++nf) {
      float2 po = smRed[(((wm^1)*2 + wn)*2 + nf)*16 + l15];
      float S = s2[nf] + po.x, Q = q2[nf] + po.y;
      m[nf] = S * (1.f/128.f);
      rs[nf] = rsqrtf(Q * (1.f/128.f) - m[nf]*m[nf] + 1e-5f);
    }
    #pragma unroll
    for (int mf = 0; mf < 4; ++mf) {
      float4 gq  = *(const float4*)(g2 + nb + mf*16);
      float4 beq = *(const float4*)(be2 + nb + mf*16);
      #pragma unroll
      for (int nf = 0; nf < 2; ++nf) {
        int e = wn*32 + nf*16 + l15;
        short4v o;
        #pragma unroll
        for (int j = 0; j < 4; ++j) {
          float val = (acc2[mf][nf][j] - m[nf]) * rs[nf] * ((const float*)&gq)[j] + ((const float*)&beq)[j];
          o[j] = f2bf(silu(val));
        }
        int bo = (e*256 + (nb + mf*16)*2) ^ ((e & 7) << 4);
        *(short4v*)((char*)smX + bo) = o;
      }
    }
  }
  __syncthreads();                                   // B5 (x2 visible)

  // ---- GEMM3-T: phiT[m3][e] = sum_k W3t[m3][k] * x2[e][k]; wave w owns e = w*16+l15 ----
  {
    f32x4 acc3 = {};
    const ushort* A3 = W3t + (size_t)l15 * 128 + lh*8;
    int e = w*16 + l15;
    #pragma unroll
    for (int k0 = 0; k0 < 4; ++k0) {
      short8 a = *(const short8*)(A3 + k0*32);
      int bo = (e*256 + k0*64 + lh*16) ^ ((e & 7) << 4);
      short8 b = *(const short8*)((char*)smX + bo);
      acc3 = __builtin_amdgcn_mfma_f32_16x16x32_bf16(a, b, acc3, 0, 0, 0);
    }
    // lane holds phi[e][m3] for m3 = lh*4..lh*4+3  -> smPhi row stride 20 f32
    *(float4*)(smPhi + e*20 + lh*4) = *(float4*)&acc3;
  }
  __syncthreads();                                   // B6 (phi visible)

  // ---- trans[l][k] = sum_j cd[j][k]*phi[j][l]; scatter-add to agg[row] ----
  {
    int e = tid >> 2, qd = tid & 3;
    int re = smRow[e];
    float em = smEM[e];
    const float* cd = smCd + e*9;
    const float* ph = smPhi + e*20;
    for (int idx = qd; idx < 9; idx += 4) {
      int l2 = idx / 3, k = idx - l2*3;
      float t = cd[k]*ph[l2] + cd[3+k]*ph[3+l2] + cd[6+k]*ph[6+l2];
      unsafeAtomicAdd(&agg[(size_t)re*9 + idx], t * em);
    }
  }
}

__global__ void finalize_kernel(const float* __restrict__ coord, const float* __restrict__ node_mask,
                                const float* __restrict__ agg, float* __restrict__ out) {
  int i = blockIdx.x * 256 + threadIdx.x;
  if (i < NN*9) {
    int n = i / 9;
    out[i] = (coord[i] + agg[i] * 0.01f) * node_mask[n];
  }
}

extern "C" void kernel_launch(void* const* d_in, const int* in_sizes, int n_in,
                              void* d_out, int out_size, void* d_ws, size_t ws_size,
                              hipStream_t stream) {
  const float* h          = (const float*)d_in[0];
  const float* coord      = (const float*)d_in[1];
  const float* coord_diff = (const float*)d_in[2];
  const float* edge_attr  = (const float*)d_in[3];
  const float* edge_mask  = (const float*)d_in[4];
  const float* node_mask  = (const float*)d_in[5];
  const int*   rowi       = (const int*)d_in[6];
  const int*   coli       = (const int*)d_in[7];
  const float* W1  = (const float*)d_in[8];
  const float* b1  = (const float*)d_in[9];
  const float* g1  = (const float*)d_in[10];
  const float* be1 = (const float*)d_in[11];
  const float* W2  = (const float*)d_in[12];
  const float* b2  = (const float*)d_in[13];
  const float* g2  = (const float*)d_in[14];
  const float* be2 = (const float*)d_in[15];
  const float* W3  = (const float*)d_in[16];

  char* ws = (char*)d_ws;
  float*  agg = (float*)ws;                        // 1,800,000 B
  ushort* W1t = (ushort*)(ws + 1800064);           // 65,536 B
  ushort* W2t = (ushort*)(ws + 1865600);           // 32,768 B
  ushort* W3t = (ushort*)(ws + 1898368);           // 4,096 B
  ushort* hb  = (ushort*)(ws + 1902464);           // 12,800,000 B
  bool use_hb = ws_size >= (size_t)1902464 + 12800000;

  prep_kernel<<<3325 + (NN*9 + 255)/256, 256, 0, stream>>>(h, hb, W1, W2, W3, W1t, W2t, W3t, agg);
  if (use_hb) {
    edge_kernel<true><<<EE/64, 256, 0, stream>>>(h, hb, W1t, W2t, W3t, W1,
        b1, g1, be1, b2, g2, be2, edge_attr, edge_mask, coord_diff, rowi, coli, agg);
  } else {
    edge_kernel<false><<<EE/64, 256, 0, stream>>>(h, hb, W1t, W2t, W3t, W1,
        b1, g1, be1, b2, g2, be2, edge_attr, edge_mask, coord_diff, rowi, coli, agg);
  }
  finalize_kernel<<<(NN*9 + 255)/256, 256, 0, stream>>>(coord, node_mask, agg, (float*)d_out);
}